// Round 1
// baseline (430.172 us; speedup 1.0000x reference)
//
#include <hip/hip_runtime.h>

#define N_NODES 100000
#define N_EDGES 1600000
#define DIM 64

// ---------------------------------------------------------------------------
// Kernel 1: zero the accumulator (d_out doubles as h[N_NODES][64])
// ---------------------------------------------------------------------------
__global__ void zero_kernel(float4* __restrict__ p, int n4) {
    int stride = gridDim.x * blockDim.x;
    for (int i = blockIdx.x * blockDim.x + threadIdx.x; i < n4; i += stride) {
        p[i] = float4{0.f, 0.f, 0.f, 0.f};
    }
}

// ---------------------------------------------------------------------------
// Kernel 2: per-edge gather-scale-scatter.
// One wave handles one edge per iteration; lane i = feature dim i.
// 64 consecutive f32 atomics per edge -> 4 contiguous cachelines, TCC-coalesced.
// ---------------------------------------------------------------------------
__global__ void scatter_kernel(const float* __restrict__ feat,
                               const float* __restrict__ edge_w,
                               const int* __restrict__ src,
                               const int* __restrict__ dst,
                               float* __restrict__ h,
                               int n_edges) {
    int lane = threadIdx.x & 63;
    int wave = (int)((blockIdx.x * blockDim.x + threadIdx.x) >> 6);
    int total_waves = (int)((gridDim.x * blockDim.x) >> 6);
    for (int e = wave; e < n_edges; e += total_waves) {
        int s = src[e];
        int d = dst[e];
        float w = edge_w[e];
        float v = feat[(long)s * DIM + lane] * w;
        atomicAdd(&h[(long)d * DIM + lane], v);
    }
}

// ---------------------------------------------------------------------------
// Kernel 3: in-place row-local linear: out[i] = h[i] @ W + b.
// W staged in LDS; h[k] broadcast via __shfl; lane j owns output column j.
// Safe in-place: each row read fully (one load) before its write, one wave/row.
// ---------------------------------------------------------------------------
__global__ void linear_kernel(float* __restrict__ h,
                              const float* __restrict__ W,
                              const float* __restrict__ bias,
                              int n_nodes) {
    __shared__ float Ws[DIM * DIM];
    __shared__ float bs[DIM];
    for (int i = threadIdx.x; i < DIM * DIM; i += blockDim.x) Ws[i] = W[i];
    if (threadIdx.x < DIM) bs[threadIdx.x] = bias[threadIdx.x];
    __syncthreads();

    int lane = threadIdx.x & 63;
    int wave_in_block = threadIdx.x >> 6;
    int waves_per_block = blockDim.x >> 6;
    int gwave = blockIdx.x * waves_per_block + wave_in_block;
    int total_waves = gridDim.x * waves_per_block;

    for (int row = gwave; row < n_nodes; row += total_waves) {
        float hval = h[(long)row * DIM + lane];
        float acc = bs[lane];
#pragma unroll
        for (int k = 0; k < DIM; ++k) {
            float hk = __shfl(hval, k, 64);
            acc = fmaf(hk, Ws[k * DIM + lane], acc);
        }
        h[(long)row * DIM + lane] = acc;
    }
}

// ---------------------------------------------------------------------------
extern "C" void kernel_launch(void* const* d_in, const int* in_sizes, int n_in,
                              void* d_out, int out_size, void* d_ws, size_t ws_size,
                              hipStream_t stream) {
    const float* feat   = (const float*)d_in[0];
    const float* edge_w = (const float*)d_in[1];
    const int*   src    = (const int*)d_in[2];
    const int*   dst    = (const int*)d_in[3];
    const float* weight = (const float*)d_in[4];
    const float* bias   = (const float*)d_in[5];
    float* out = (float*)d_out;

    // 1) zero accumulator (d_out) : 6.4M floats = 1.6M float4
    int n4 = N_NODES * DIM / 4;
    zero_kernel<<<2048, 256, 0, stream>>>((float4*)out, n4);

    // 2) scatter-add edges into d_out
    scatter_kernel<<<2048, 256, 0, stream>>>(feat, edge_w, src, dst, out, N_EDGES);

    // 3) in-place linear
    linear_kernel<<<2048, 256, 0, stream>>>(out, weight, bias, N_NODES);
}